// Round 11
// baseline (208.214 us; speedup 1.0000x reference)
//
#include <hip/hip_runtime.h>
#include <stdint.h>

// Problem constants
#define Bc 2
#define Sc 2048
#define Ec 1024
#define Hc 16
#define Dc 64
#define Mc (Bc*Sc)   // 4096 rows

typedef __attribute__((ext_vector_type(4))) float f32x4;
typedef __attribute__((ext_vector_type(8))) short bf16x8v;

// 0.125 * log2(e): folded into Q at the GEMM epilogue -> scores exit QK^T in exp2 domain
#define SCL 0.1803368801f

__device__ __forceinline__ unsigned short f2bf(float f){
  unsigned int u = __float_as_uint(f);
  u += 0x7FFFu + ((u >> 16) & 1u);     // RNE
  return (unsigned short)(u >> 16);
}

// -------- fused prep: X fp32->bf16 (blocks 0..4095) + W->WT bf16 (blocks 4096..5119) ----
__global__ __launch_bounds__(256) void k_prep(const float* __restrict__ X,
                                              unsigned short* __restrict__ Xb,
                                              const float* __restrict__ W0, const float* __restrict__ W1,
                                              const float* __restrict__ W2, const float* __restrict__ W3,
                                              unsigned short* __restrict__ WT4){
  __shared__ float st[64][65];
  int bx = blockIdx.x, t = threadIdx.x;
  if (bx < 4096){
    int i = bx*256 + t;
    float4 v = ((const float4*)X)[i];
    ushort4 o;
    o.x = f2bf(v.x); o.y = f2bf(v.y); o.z = f2bf(v.z); o.w = f2bf(v.w);
    ((ushort4*)Xb)[i] = o;
  } else {
    int id = bx - 4096;
    int z = id >> 8, rem = id & 255;
    int k0 = (rem >> 4)*64, n0 = (rem & 15)*64;
    const float* W = (z==0)?W0 : (z==1)?W1 : (z==2)?W2 : W3;
    unsigned short* o = WT4 + (size_t)z * Ec * Ec;
    #pragma unroll
    for (int i=0;i<16;i++){ int lin=i*256+t; int r=lin>>6, c=lin&63;
      st[r][c] = W[(size_t)(k0+r)*Ec + n0+c]; }
    __syncthreads();
    #pragma unroll
    for (int i=0;i<16;i++){ int lin=i*256+t; int nn=lin>>6, kk=lin&63;
      o[(size_t)(n0+nn)*Ec + k0+kk] = f2bf(st[kk][nn]); }
  }
}

// ------------- FUSED QKV GEMM: one A-staging feeds Q,K,V (3x MFMA per barrier) -------------
// BM=128, BN=64, BK=32, double-buffered LDS, one barrier per K-iter.
// Outputs: z=0 Q*SCL [B][H][S][D], z=1 K [B][H][S][D], z=2 V^T [B][H][D][S], all bf16.
__global__ __launch_bounds__(256,2) void k_qkv(const unsigned short* __restrict__ A,
                                               const unsigned short* __restrict__ WT4,
                                               const float* __restrict__ bq,
                                               const float* __restrict__ bk,
                                               const float* __restrict__ bv,
                                               unsigned short* __restrict__ QKV){
  __shared__ unsigned short sA[2][128*32];
  __shared__ unsigned short sB[2][3][64*32];
  int bm = blockIdx.y, bn = blockIdx.x;    // bn: 0..15 over N=1024
  int t = threadIdx.x, w = t>>6, lane = t&63, quad = lane>>4, m16 = lane&15;
  int wm = w>>1, wn = w&1;
  f32x4 acc[3][4][2];
  #pragma unroll
  for (int z=0;z<3;z++)
    #pragma unroll
    for (int i=0;i<4;i++)
      #pragma unroll
      for (int j=0;j<2;j++) acc[z][i][j] = (f32x4){0.f,0.f,0.f,0.f};

  auto stage = [&](int kt, int buf){
    #pragma unroll
    for (int i=0;i<2;i++){
      int cb = (w*2 + i)*64;               // wave-uniform chunk base; A: 512 chunks
      int L = cb + lane;
      int row = L>>2, c = (L&3)*8;
      const unsigned short* ga = A + (size_t)(bm*128 + row)*Ec + kt*32 + c;
      __builtin_amdgcn_global_load_lds((const __attribute__((address_space(1))) void*)ga,
          (__attribute__((address_space(3))) void*)(&sA[buf][0] + cb*8), 16, 0, 0);
    }
    #pragma unroll
    for (int z=0;z<3;z++){
      int cb = w*64;                       // B slice: 256 chunks, 1/thread
      int L = cb + lane;
      int row = L>>2, c = (L&3)*8;
      const unsigned short* gb = WT4 + (size_t)z*Ec*Ec + (size_t)(bn*64 + row)*Ec + kt*32 + c;
      __builtin_amdgcn_global_load_lds((const __attribute__((address_space(1))) void*)gb,
          (__attribute__((address_space(3))) void*)(&sB[buf][z][0] + cb*8), 16, 0, 0);
    }
  };

  stage(0, 0);
  for (int kt=0; kt<Ec/32; ++kt){
    int cur = kt & 1;
    __syncthreads();
    if (kt+1 < Ec/32) stage(kt+1, cur^1);
    bf16x8v af[4];
    #pragma unroll
    for (int s=0;s<4;s++)
      af[s] = *(const bf16x8v*)(&sA[cur][0] + (wm*64 + s*16 + m16)*32 + quad*8);
    #pragma unroll
    for (int z=0;z<3;z++){
      bf16x8v bfr[2];
      #pragma unroll
      for (int s=0;s<2;s++)
        bfr[s] = *(const bf16x8v*)(&sB[cur][z][0] + (wn*32 + s*16 + m16)*32 + quad*8);
      #pragma unroll
      for (int sm=0;sm<4;sm++)
        #pragma unroll
        for (int sn=0;sn<2;sn++)
          acc[z][sm][sn] = __builtin_amdgcn_mfma_f32_16x16x32_bf16(af[sm], bfr[sn], acc[z][sm][sn], 0,0,0);
    }
  }
  // epilogue: C/D layout row = quad*4+r, col = lane&15
  #pragma unroll
  for (int z=0;z<3;z++){
    const float* bias = (z==0)?bq : (z==1)?bk : bv;
    unsigned short* Out = QKV + (size_t)z * (size_t)Mc * Ec;
    #pragma unroll
    for (int sm=0;sm<4;sm++){
      int row0 = bm*128 + wm*64 + sm*16 + quad*4;
      int bidx = row0 >> 11;
      #pragma unroll
      for (int sn=0;sn<2;sn++){
        int col = bn*64 + wn*32 + sn*16 + m16;
        float bb = bias[col];
        int h = col >> 6, d = col & 63;
        if (z == 2){
          int s0 = row0 & (Sc-1);
          ushort4 pk;
          pk.x = f2bf(acc[z][sm][sn][0] + bb);
          pk.y = f2bf(acc[z][sm][sn][1] + bb);
          pk.z = f2bf(acc[z][sm][sn][2] + bb);
          pk.w = f2bf(acc[z][sm][sn][3] + bb);
          *(ushort4*)(Out + (((size_t)bidx*Hc + h)*Dc + d)*Sc + s0) = pk;
        } else {
          float sc_ = (z==0) ? SCL : 1.0f;   // fold 0.125*log2e into Q
          #pragma unroll
          for (int r=0;r<4;r++){
            int s = (row0 + r) & (Sc-1);
            Out[(((size_t)bidx*Hc + h)*Sc + s)*Dc + d] = f2bf((acc[z][sm][sn][r] + bb)*sc_);
          }
        }
      }
    }
  }
}

// ------------- out-proj GEMM: BK=32, dbuf LDS, BN=64, fp32 out [4096][1024] -------------
__global__ __launch_bounds__(256,4) void k_gemm1(const unsigned short* __restrict__ A,
                                                 const unsigned short* __restrict__ WT,
                                                 const float* __restrict__ bias,
                                                 float* __restrict__ Out){
  __shared__ unsigned short sA[2][128*32];
  __shared__ unsigned short sB[2][64*32];
  int bm = blockIdx.y, bn = blockIdx.x;
  int t = threadIdx.x, w = t>>6, lane = t&63, quad = lane>>4, m16 = lane&15;
  int wm = w>>1, wn = w&1;
  f32x4 acc[4][2];
  #pragma unroll
  for (int i=0;i<4;i++)
    #pragma unroll
    for (int j=0;j<2;j++) acc[i][j] = (f32x4){0.f,0.f,0.f,0.f};

  auto stage = [&](int kt, int buf){
    #pragma unroll
    for (int i=0;i<2;i++){
      int cb = (w*2 + i)*64;
      int L = cb + lane;
      int row = L>>2, c = (L&3)*8;
      const unsigned short* ga = A + (size_t)(bm*128 + row)*Ec + kt*32 + c;
      __builtin_amdgcn_global_load_lds((const __attribute__((address_space(1))) void*)ga,
          (__attribute__((address_space(3))) void*)(&sA[buf][0] + cb*8), 16, 0, 0);
    }
    {
      int cb = w*64;
      int L = cb + lane;
      int row = L>>2, c = (L&3)*8;
      const unsigned short* gb = WT + (size_t)(bn*64 + row)*Ec + kt*32 + c;
      __builtin_amdgcn_global_load_lds((const __attribute__((address_space(1))) void*)gb,
          (__attribute__((address_space(3))) void*)(&sB[buf][0] + cb*8), 16, 0, 0);
    }
  };

  stage(0, 0);
  for (int kt=0; kt<Ec/32; ++kt){
    int cur = kt & 1;
    __syncthreads();
    if (kt+1 < Ec/32) stage(kt+1, cur^1);
    bf16x8v af[4], bfr[2];
    #pragma unroll
    for (int s=0;s<4;s++)
      af[s]  = *(const bf16x8v*)(&sA[cur][0] + (wm*64 + s*16 + m16)*32 + quad*8);
    #pragma unroll
    for (int s=0;s<2;s++)
      bfr[s] = *(const bf16x8v*)(&sB[cur][0] + (wn*32 + s*16 + m16)*32 + quad*8);
    #pragma unroll
    for (int sm=0;sm<4;sm++)
      #pragma unroll
      for (int sn=0;sn<2;sn++)
        acc[sm][sn] = __builtin_amdgcn_mfma_f32_16x16x32_bf16(af[sm], bfr[sn], acc[sm][sn], 0,0,0);
  }
  #pragma unroll
  for (int sm=0;sm<4;sm++){
    int row0 = bm*128 + wm*64 + sm*16 + quad*4;
    #pragma unroll
    for (int sn=0;sn<2;sn++){
      int col = bn*64 + wn*32 + sn*16 + m16;
      float bb = bias[col];
      #pragma unroll
      for (int r=0;r<4;r++)
        Out[(size_t)(row0+r)*Ec + col] = acc[sm][sn][r] + bb;
    }
  }
}

// ------------- flash attention (r6 form): paired q-tiles, static-max exp2 softmax ----------
__device__ __forceinline__ void attn_tile(const unsigned short* sK, const unsigned short* sVT,
                                          unsigned short* pw, bf16x8v qf0, bf16x8v qf1,
                                          bf16x8v ones, f32x4& li, f32x4* Oa,
                                          int kbase, int qw, int quad, int m16){
  int sw = m16 & 7;
  // S^T[j][q] = sum_d K[j][d] Q'[q][d]; C-layout: j=kbase+sm*16+quad*4+r, q=qw+m16
  f32x4 sc[4];
  #pragma unroll
  for (int sm=0;sm<4;sm++){
    int row = sm*16 + m16;
    bf16x8v kf0 = *(const bf16x8v*)(sK + row*64 + ((quad  )^sw)*8);
    bf16x8v kf1 = *(const bf16x8v*)(sK + row*64 + ((quad+4)^sw)*8);
    f32x4 a = (f32x4){0.f,0.f,0.f,0.f};
    a = __builtin_amdgcn_mfma_f32_16x16x32_bf16(kf0, qf0, a, 0,0,0);
    a = __builtin_amdgcn_mfma_f32_16x16x32_bf16(kf1, qf1, a, 0,0,0);
    sc[sm] = a;
  }
  // p = exp2(s); zero masked entries (diagonal tiles only)
  if (kbase + 63 > qw){
    #pragma unroll
    for (int sm=0;sm<4;sm++)
      #pragma unroll
      for (int r=0;r<4;r++){
        int kg = kbase + sm*16 + quad*4 + r;
        float p = exp2f(sc[sm][r]);
        sc[sm][r] = (kg <= qw + m16) ? p : 0.0f;
      }
  } else {
    #pragma unroll
    for (int sm=0;sm<4;sm++)
      #pragma unroll
      for (int r=0;r<4;r++) sc[sm][r] = exp2f(sc[sm][r]);
  }

  // P^T C-layout -> sP[q][j] (A-layout source), packed swizzled 8B writes
  #pragma unroll
  for (int sm=0;sm<4;sm++){
    ushort4 pk;
    pk.x = f2bf(sc[sm][0]); pk.y = f2bf(sc[sm][1]);
    pk.z = f2bf(sc[sm][2]); pk.w = f2bf(sc[sm][3]);
    int chunk = sm*2 + (quad>>1);
    *(ushort4*)(pw + m16*64 + (chunk^sw)*8 + (quad&1)*4) = pk;
  }
  bf16x8v pf0 = *(const bf16x8v*)(pw + m16*64 + ((quad  )^sw)*8);
  bf16x8v pf1 = *(const bf16x8v*)(pw + m16*64 + ((quad+4)^sw)*8);

  // li[q] += sum_j P[q][j] via ones-MFMA; lands in C-layout row q=quad*4+r (matches O rows)
  li = __builtin_amdgcn_mfma_f32_16x16x32_bf16(pf0, ones, li, 0,0,0);
  li = __builtin_amdgcn_mfma_f32_16x16x32_bf16(pf1, ones, li, 0,0,0);

  // O[q][d] += P·V ; B-frag from V^T rows d = tt*16+m16
  #pragma unroll
  for (int tt=0;tt<4;tt++){
    int rowv = tt*16 + m16;
    bf16x8v vf0 = *(const bf16x8v*)(sVT + rowv*64 + ((quad  )^sw)*8);
    bf16x8v vf1 = *(const bf16x8v*)(sVT + rowv*64 + ((quad+4)^sw)*8);
    Oa[tt] = __builtin_amdgcn_mfma_f32_16x16x32_bf16(pf0, vf0, Oa[tt], 0,0,0);
    Oa[tt] = __builtin_amdgcn_mfma_f32_16x16x32_bf16(pf1, vf1, Oa[tt], 0,0,0);
  }
}

__global__ __launch_bounds__(256,2) void k_attn(const unsigned short* __restrict__ Qb,
                                                const unsigned short* __restrict__ Kb,
                                                const unsigned short* __restrict__ VTb,
                                                unsigned short* __restrict__ Ob){
  __shared__ unsigned short sK [64*64];    // [j][d], 16B chunks XOR-swizzled by row&7
  __shared__ unsigned short sVT[64*64];    // [d][j], same swizzle
  __shared__ unsigned short sP [4][16*64]; // per-wave P[q][j], same swizzle
  int bh = blockIdx.y;
  int qtA = (int)blockIdx.x;               // 0..15 (light)
  int qtB = 31 - qtA;                      // 16..31 (heavy); work A+B = const 33
  size_t base = (size_t)bh * Sc * Dc;
  const unsigned short* Q  = Qb  + base;
  const unsigned short* K  = Kb  + base;
  const unsigned short* VT = VTb + base;   // [d][s]
  int t = threadIdx.x, w = t>>6, lane = t&63, quad = lane>>4, m16 = lane&15;
  int qwA = qtA*64 + w*16;
  int qwB = qtB*64 + w*16;

  bf16x8v qA0 = *(const bf16x8v*)(Q + (size_t)(qwA + m16)*Dc + quad*8);
  bf16x8v qA1 = *(const bf16x8v*)(Q + (size_t)(qwA + m16)*Dc + 32 + quad*8);
  bf16x8v qB0 = *(const bf16x8v*)(Q + (size_t)(qwB + m16)*Dc + quad*8);
  bf16x8v qB1 = *(const bf16x8v*)(Q + (size_t)(qwB + m16)*Dc + 32 + quad*8);

  bf16x8v ones;
  #pragma unroll
  for (int i=0;i<8;i++) ones[i] = (short)0x3F80;   // bf16 1.0

  f32x4 OaA[4], OaB[4];
  #pragma unroll
  for (int i=0;i<4;i++){ OaA[i] = (f32x4){0.f,0.f,0.f,0.f}; OaB[i] = (f32x4){0.f,0.f,0.f,0.f}; }
  f32x4 liA = (f32x4){0.f,0.f,0.f,0.f}, liB = (f32x4){0.f,0.f,0.f,0.f};

  unsigned short* pw = &sP[w][0];

  for (int kt=0; kt<=qtB; ++kt){
    int kbase = kt*64;
    #pragma unroll
    for (int i=0;i<2;i++){
      int cb = (w*2 + i)*64;              // wave-uniform chunk base
      int L = cb + lane;
      int row = L>>3, p = L&7, c = p ^ (row&7);
      const unsigned short* gk = K  + (size_t)(kbase+row)*Dc + c*8;
      const unsigned short* gv = VT + (size_t)row*Sc + kbase + c*8;
      __builtin_amdgcn_global_load_lds((const __attribute__((address_space(1))) void*)gk,
          (__attribute__((address_space(3))) void*)(sK + cb*8), 16, 0, 0);
      __builtin_amdgcn_global_load_lds((const __attribute__((address_space(1))) void*)gv,
          (__attribute__((address_space(3))) void*)(sVT + cb*8), 16, 0, 0);
    }
    __syncthreads();

    if (kt <= qtA)
      attn_tile(sK, sVT, pw, qA0, qA1, ones, liA, OaA, kbase, qwA, quad, m16);
    attn_tile(sK, sVT, pw, qB0, qB1, ones, liB, OaB, kbase, qwB, quad, m16);

    __syncthreads();
  }

  // epilogue: O rows s = qw+quad*4+r, cols e = h*64 + tt*16 + m16; li already per-row
  int b = bh >> 4, h = bh & 15;
  float iA[4], iB[4];
  #pragma unroll
  for (int r=0;r<4;r++){ iA[r] = 1.0f/liA[r]; iB[r] = 1.0f/liB[r]; }
  #pragma unroll
  for (int tt=0;tt<4;tt++)
    #pragma unroll
    for (int r=0;r<4;r++){
      int e = h*64 + tt*16 + m16;
      int sA_ = qwA + quad*4 + r;
      int sB_ = qwB + quad*4 + r;
      Ob[((size_t)b*Sc + sA_)*Ec + e] = f2bf(OaA[tt][r]*iA[r]);
      Ob[((size_t)b*Sc + sB_)*Ec + e] = f2bf(OaB[tt][r]*iB[r]);
    }
}

extern "C" void kernel_launch(void* const* d_in, const int* in_sizes, int n_in,
                              void* d_out, int out_size, void* d_ws, size_t ws_size,
                              hipStream_t stream){
  const float* X  = (const float*)d_in[0];
  const float* Wq = (const float*)d_in[1];
  const float* bq = (const float*)d_in[2];
  const float* Wk = (const float*)d_in[3];
  const float* bk = (const float*)d_in[4];
  const float* Wv = (const float*)d_in[5];
  const float* bv = (const float*)d_in[6];
  const float* Wo = (const float*)d_in[7];
  const float* bo = (const float*)d_in[8];

  uint8_t* ws = (uint8_t*)d_ws;
  unsigned short* Xb  = (unsigned short*)(ws);                    // 8 MB
  unsigned short* WT4 = (unsigned short*)(ws + (size_t)(8u<<20)); // 8 MB (WqT,WkT,WvT,WoT)
  unsigned short* QKV = (unsigned short*)(ws + (size_t)(16u<<20));// 24 MB (Q,K,V^T)
  unsigned short* ATT = (unsigned short*)(ws + (size_t)(40u<<20));// 8 MB

  k_prep<<<dim3(5120), 256, 0, stream>>>(X, Xb, Wq, Wk, Wv, Wo, WT4);
  k_qkv<<<dim3(16,32), 256, 0, stream>>>(Xb, WT4, bq, bk, bv, QKV);
  k_attn<<<dim3(16,32), 256, 0, stream>>>(QKV, QKV + (size_t)Mc*Ec, QKV + 2*(size_t)Mc*Ec, ATT);
  k_gemm1<<<dim3(16,32), 256, 0, stream>>>(ATT, WT4 + (size_t)3*Ec*Ec, bo, (float*)d_out);
}

// Round 12
// 182.408 us; speedup vs baseline: 1.1415x; 1.1415x over previous
//
#include <hip/hip_runtime.h>
#include <stdint.h>

// Problem constants
#define Bc 2
#define Sc 2048
#define Ec 1024
#define Hc 16
#define Dc 64
#define Mc (Bc*Sc)   // 4096 rows

typedef __attribute__((ext_vector_type(4))) float f32x4;
typedef __attribute__((ext_vector_type(8))) short bf16x8v;

// 0.125 * log2(e): folded into Q at the GEMM epilogue -> scores exit QK^T in exp2 domain
#define SCL 0.1803368801f

__device__ __forceinline__ unsigned short f2bf(float f){
  unsigned int u = __float_as_uint(f);
  u += 0x7FFFu + ((u >> 16) & 1u);     // RNE
  return (unsigned short)(u >> 16);
}

#define GLDS(src, dst) __builtin_amdgcn_global_load_lds( \
    (const __attribute__((address_space(1))) void*)(src), \
    (__attribute__((address_space(3))) void*)(dst), 16, 0, 0)

// -------- fused prep: X fp32->bf16 (blocks 0..4095) + W->WT bf16 (blocks 4096..5119) ----
__global__ __launch_bounds__(256) void k_prep(const float* __restrict__ X,
                                              unsigned short* __restrict__ Xb,
                                              const float* __restrict__ W0, const float* __restrict__ W1,
                                              const float* __restrict__ W2, const float* __restrict__ W3,
                                              unsigned short* __restrict__ WT4){
  __shared__ float st[64][65];
  int bx = blockIdx.x, t = threadIdx.x;
  if (bx < 4096){
    int i = bx*256 + t;
    float4 v = ((const float4*)X)[i];
    ushort4 o;
    o.x = f2bf(v.x); o.y = f2bf(v.y); o.z = f2bf(v.z); o.w = f2bf(v.w);
    ((ushort4*)Xb)[i] = o;
  } else {
    int id = bx - 4096;
    int z = id >> 8, rem = id & 255;
    int k0 = (rem >> 4)*64, n0 = (rem & 15)*64;
    const float* W = (z==0)?W0 : (z==1)?W1 : (z==2)?W2 : W3;
    unsigned short* o = WT4 + (size_t)z * Ec * Ec;
    #pragma unroll
    for (int i=0;i<16;i++){ int lin=i*256+t; int r=lin>>6, c=lin&63;
      st[r][c] = W[(size_t)(k0+r)*Ec + n0+c]; }
    __syncthreads();
    #pragma unroll
    for (int i=0;i<16;i++){ int lin=i*256+t; int nn=lin>>6, kk=lin&63;
      o[(size_t)(n0+nn)*Ec + k0+kk] = f2bf(st[kk][nn]); }
  }
}

// ------------- FUSED QKV GEMM: BK=64 (XOR-swizzled LDS), dbuf, 48 MFMA per barrier -------------
// BM=128, BN=64. Outputs: z=0 Q*SCL [B][H][S][D], z=1 K [B][H][S][D], z=2 V^T [B][H][D][S].
__global__ __launch_bounds__(256,2) void k_qkv(const unsigned short* __restrict__ A,
                                               const unsigned short* __restrict__ WT4,
                                               const float* __restrict__ bq,
                                               const float* __restrict__ bk,
                                               const float* __restrict__ bv,
                                               unsigned short* __restrict__ QKV){
  __shared__ unsigned short sA[2][128*64];     // 16 KB per buf, swizzled: slot p holds chunk p^(row&7)
  __shared__ unsigned short sB[2][3][64*64];   // 8 KB per slice
  int bm = blockIdx.y, bn = blockIdx.x;        // bn: 0..15 over N=1024
  int t = threadIdx.x, w = t>>6, lane = t&63, quad = lane>>4, m16 = lane&15;
  int wm = w>>1, wn = w&1, sw = m16 & 7;
  f32x4 acc[3][4][2];
  #pragma unroll
  for (int z=0;z<3;z++)
    #pragma unroll
    for (int i=0;i<4;i++)
      #pragma unroll
      for (int j=0;j<2;j++) acc[z][i][j] = (f32x4){0.f,0.f,0.f,0.f};

  auto stage = [&](int kt, int buf){
    #pragma unroll
    for (int i=0;i<4;i++){                     // A: 128x64 = 1024 chunks, 4/thread
      int cb = (w*4 + i)*64;
      int L = cb + lane;
      int row = L>>3, c = (L&7) ^ (row&7);
      GLDS(A + (size_t)(bm*128 + row)*Ec + kt*64 + c*8, &sA[buf][0] + cb*8);
    }
    #pragma unroll
    for (int z=0;z<3;z++)
      #pragma unroll
      for (int i=0;i<2;i++){                   // each B slice: 64x64 = 512 chunks, 2/thread
        int cb = (w*2 + i)*64;
        int L = cb + lane;
        int row = L>>3, c = (L&7) ^ (row&7);
        GLDS(WT4 + (size_t)z*Ec*Ec + (size_t)(bn*64 + row)*Ec + kt*64 + c*8,
             &sB[buf][z][0] + cb*8);
      }
  };

  stage(0, 0);
  for (int kt=0; kt<Ec/64; ++kt){
    int cur = kt & 1;
    __syncthreads();
    if (kt+1 < Ec/64) stage(kt+1, cur^1);
    bf16x8v af[4][2];
    #pragma unroll
    for (int s=0;s<4;s++){
      int row = wm*64 + s*16 + m16;
      af[s][0] = *(const bf16x8v*)(&sA[cur][0] + row*64 + ((quad  )^sw)*8);
      af[s][1] = *(const bf16x8v*)(&sA[cur][0] + row*64 + ((quad+4)^sw)*8);
    }
    #pragma unroll
    for (int z=0;z<3;z++){
      bf16x8v bfr[2][2];
      #pragma unroll
      for (int sn=0;sn<2;sn++){
        int rowb = wn*32 + sn*16 + m16;
        bfr[sn][0] = *(const bf16x8v*)(&sB[cur][z][0] + rowb*64 + ((quad  )^sw)*8);
        bfr[sn][1] = *(const bf16x8v*)(&sB[cur][z][0] + rowb*64 + ((quad+4)^sw)*8);
      }
      #pragma unroll
      for (int sm=0;sm<4;sm++)
        #pragma unroll
        for (int sn=0;sn<2;sn++){
          acc[z][sm][sn] = __builtin_amdgcn_mfma_f32_16x16x32_bf16(af[sm][0], bfr[sn][0], acc[z][sm][sn], 0,0,0);
          acc[z][sm][sn] = __builtin_amdgcn_mfma_f32_16x16x32_bf16(af[sm][1], bfr[sn][1], acc[z][sm][sn], 0,0,0);
        }
    }
  }
  // epilogue: C/D layout row = quad*4+r, col = lane&15
  #pragma unroll
  for (int z=0;z<3;z++){
    const float* bias = (z==0)?bq : (z==1)?bk : bv;
    unsigned short* Out = QKV + (size_t)z * (size_t)Mc * Ec;
    #pragma unroll
    for (int sm=0;sm<4;sm++){
      int row0 = bm*128 + wm*64 + sm*16 + quad*4;
      int bidx = row0 >> 11;
      #pragma unroll
      for (int sn=0;sn<2;sn++){
        int col = bn*64 + wn*32 + sn*16 + m16;
        float bb = bias[col];
        int h = col >> 6, d = col & 63;
        if (z == 2){
          int s0 = row0 & (Sc-1);
          ushort4 pk;
          pk.x = f2bf(acc[z][sm][sn][0] + bb);
          pk.y = f2bf(acc[z][sm][sn][1] + bb);
          pk.z = f2bf(acc[z][sm][sn][2] + bb);
          pk.w = f2bf(acc[z][sm][sn][3] + bb);
          *(ushort4*)(Out + (((size_t)bidx*Hc + h)*Dc + d)*Sc + s0) = pk;
        } else {
          float sc_ = (z==0) ? SCL : 1.0f;   // fold 0.125*log2e into Q
          #pragma unroll
          for (int r=0;r<4;r++){
            int s = (row0 + r) & (Sc-1);
            Out[(((size_t)bidx*Hc + h)*Sc + s)*Dc + d] = f2bf((acc[z][sm][sn][r] + bb)*sc_);
          }
        }
      }
    }
  }
}

// ------------- out-proj GEMM: BK=64 swizzled, dbuf, fp32 out [4096][1024] -------------
__global__ __launch_bounds__(256,2) void k_gemm1(const unsigned short* __restrict__ A,
                                                 const unsigned short* __restrict__ WT,
                                                 const float* __restrict__ bias,
                                                 float* __restrict__ Out){
  __shared__ unsigned short sA[2][128*64];
  __shared__ unsigned short sB[2][64*64];
  int bm = blockIdx.y, bn = blockIdx.x;
  int t = threadIdx.x, w = t>>6, lane = t&63, quad = lane>>4, m16 = lane&15;
  int wm = w>>1, wn = w&1, sw = m16 & 7;
  f32x4 acc[4][2];
  #pragma unroll
  for (int i=0;i<4;i++)
    #pragma unroll
    for (int j=0;j<2;j++) acc[i][j] = (f32x4){0.f,0.f,0.f,0.f};

  auto stage = [&](int kt, int buf){
    #pragma unroll
    for (int i=0;i<4;i++){
      int cb = (w*4 + i)*64;
      int L = cb + lane;
      int row = L>>3, c = (L&7) ^ (row&7);
      GLDS(A + (size_t)(bm*128 + row)*Ec + kt*64 + c*8, &sA[buf][0] + cb*8);
    }
    #pragma unroll
    for (int i=0;i<2;i++){
      int cb = (w*2 + i)*64;
      int L = cb + lane;
      int row = L>>3, c = (L&7) ^ (row&7);
      GLDS(WT + (size_t)(bn*64 + row)*Ec + kt*64 + c*8, &sB[buf][0] + cb*8);
    }
  };

  stage(0, 0);
  for (int kt=0; kt<Ec/64; ++kt){
    int cur = kt & 1;
    __syncthreads();
    if (kt+1 < Ec/64) stage(kt+1, cur^1);
    bf16x8v af[4][2], bfr[2][2];
    #pragma unroll
    for (int s=0;s<4;s++){
      int row = wm*64 + s*16 + m16;
      af[s][0] = *(const bf16x8v*)(&sA[cur][0] + row*64 + ((quad  )^sw)*8);
      af[s][1] = *(const bf16x8v*)(&sA[cur][0] + row*64 + ((quad+4)^sw)*8);
    }
    #pragma unroll
    for (int sn=0;sn<2;sn++){
      int rowb = wn*32 + sn*16 + m16;
      bfr[sn][0] = *(const bf16x8v*)(&sB[cur][0] + rowb*64 + ((quad  )^sw)*8);
      bfr[sn][1] = *(const bf16x8v*)(&sB[cur][0] + rowb*64 + ((quad+4)^sw)*8);
    }
    #pragma unroll
    for (int sm=0;sm<4;sm++)
      #pragma unroll
      for (int sn=0;sn<2;sn++){
        acc[sm][sn] = __builtin_amdgcn_mfma_f32_16x16x32_bf16(af[sm][0], bfr[sn][0], acc[sm][sn], 0,0,0);
        acc[sm][sn] = __builtin_amdgcn_mfma_f32_16x16x32_bf16(af[sm][1], bfr[sn][1], acc[sm][sn], 0,0,0);
      }
  }
  #pragma unroll
  for (int sm=0;sm<4;sm++){
    int row0 = bm*128 + wm*64 + sm*16 + quad*4;
    #pragma unroll
    for (int sn=0;sn<2;sn++){
      int col = bn*64 + wn*32 + sn*16 + m16;
      float bb = bias[col];
      #pragma unroll
      for (int r=0;r<4;r++)
        Out[(size_t)(row0+r)*Ec + col] = acc[sm][sn][r] + bb;
    }
  }
}

// ------------- flash attention: paired q-tiles + TWO k-tiles staged per barrier phase ----------
__device__ __forceinline__ void attn_tile(const unsigned short* sK, const unsigned short* sVT,
                                          unsigned short* pw, bf16x8v qf0, bf16x8v qf1,
                                          bf16x8v ones, f32x4& li, f32x4* Oa,
                                          int kbase, int qw, int quad, int m16){
  int sw = m16 & 7;
  // S^T[j][q] = sum_d K[j][d] Q'[q][d]; C-layout: j=kbase+sm*16+quad*4+r, q=qw+m16
  f32x4 sc[4];
  #pragma unroll
  for (int sm=0;sm<4;sm++){
    int row = sm*16 + m16;
    bf16x8v kf0 = *(const bf16x8v*)(sK + row*64 + ((quad  )^sw)*8);
    bf16x8v kf1 = *(const bf16x8v*)(sK + row*64 + ((quad+4)^sw)*8);
    f32x4 a = (f32x4){0.f,0.f,0.f,0.f};
    a = __builtin_amdgcn_mfma_f32_16x16x32_bf16(kf0, qf0, a, 0,0,0);
    a = __builtin_amdgcn_mfma_f32_16x16x32_bf16(kf1, qf1, a, 0,0,0);
    sc[sm] = a;
  }
  // p = exp2(s); zero masked entries (diagonal tiles only)
  if (kbase + 63 > qw){
    #pragma unroll
    for (int sm=0;sm<4;sm++)
      #pragma unroll
      for (int r=0;r<4;r++){
        int kg = kbase + sm*16 + quad*4 + r;
        float p = exp2f(sc[sm][r]);
        sc[sm][r] = (kg <= qw + m16) ? p : 0.0f;
      }
  } else {
    #pragma unroll
    for (int sm=0;sm<4;sm++)
      #pragma unroll
      for (int r=0;r<4;r++) sc[sm][r] = exp2f(sc[sm][r]);
  }

  // P^T C-layout -> sP[q][j] (A-layout source), packed swizzled 8B writes
  #pragma unroll
  for (int sm=0;sm<4;sm++){
    ushort4 pk;
    pk.x = f2bf(sc[sm][0]); pk.y = f2bf(sc[sm][1]);
    pk.z = f2bf(sc[sm][2]); pk.w = f2bf(sc[sm][3]);
    int chunk = sm*2 + (quad>>1);
    *(ushort4*)(pw + m16*64 + (chunk^sw)*8 + (quad&1)*4) = pk;
  }
  bf16x8v pf0 = *(const bf16x8v*)(pw + m16*64 + ((quad  )^sw)*8);
  bf16x8v pf1 = *(const bf16x8v*)(pw + m16*64 + ((quad+4)^sw)*8);

  // li[q] += sum_j P[q][j] via ones-MFMA; lands in C-layout row q=quad*4+r (matches O rows)
  li = __builtin_amdgcn_mfma_f32_16x16x32_bf16(pf0, ones, li, 0,0,0);
  li = __builtin_amdgcn_mfma_f32_16x16x32_bf16(pf1, ones, li, 0,0,0);

  // O[q][d] += P·V ; B-frag from V^T rows d = tt*16+m16
  #pragma unroll
  for (int tt=0;tt<4;tt++){
    int rowv = tt*16 + m16;
    bf16x8v vf0 = *(const bf16x8v*)(sVT + rowv*64 + ((quad  )^sw)*8);
    bf16x8v vf1 = *(const bf16x8v*)(sVT + rowv*64 + ((quad+4)^sw)*8);
    Oa[tt] = __builtin_amdgcn_mfma_f32_16x16x32_bf16(pf0, vf0, Oa[tt], 0,0,0);
    Oa[tt] = __builtin_amdgcn_mfma_f32_16x16x32_bf16(pf1, vf1, Oa[tt], 0,0,0);
  }
}

__global__ __launch_bounds__(256,2) void k_attn(const unsigned short* __restrict__ Qb,
                                                const unsigned short* __restrict__ Kb,
                                                const unsigned short* __restrict__ VTb,
                                                unsigned short* __restrict__ Ob){
  __shared__ unsigned short sK [2][64*64]; // [j][d], 16B chunks XOR-swizzled by row&7
  __shared__ unsigned short sVT[2][64*64]; // [d][j], same swizzle
  __shared__ unsigned short sP [4][16*64]; // per-wave P[q][j], same swizzle
  int bh = blockIdx.y;
  int qtA = (int)blockIdx.x;               // 0..15 (light)
  int qtB = 31 - qtA;                      // 16..31 (heavy); work A+B = const 33
  size_t base = (size_t)bh * Sc * Dc;
  const unsigned short* Q  = Qb  + base;
  const unsigned short* K  = Kb  + base;
  const unsigned short* VT = VTb + base;   // [d][s]
  int t = threadIdx.x, w = t>>6, lane = t&63, quad = lane>>4, m16 = lane&15;
  int qwA = qtA*64 + w*16;
  int qwB = qtB*64 + w*16;

  bf16x8v qA0 = *(const bf16x8v*)(Q + (size_t)(qwA + m16)*Dc + quad*8);
  bf16x8v qA1 = *(const bf16x8v*)(Q + (size_t)(qwA + m16)*Dc + 32 + quad*8);
  bf16x8v qB0 = *(const bf16x8v*)(Q + (size_t)(qwB + m16)*Dc + quad*8);
  bf16x8v qB1 = *(const bf16x8v*)(Q + (size_t)(qwB + m16)*Dc + 32 + quad*8);

  bf16x8v ones;
  #pragma unroll
  for (int i=0;i<8;i++) ones[i] = (short)0x3F80;   // bf16 1.0

  f32x4 OaA[4], OaB[4];
  #pragma unroll
  for (int i=0;i<4;i++){ OaA[i] = (f32x4){0.f,0.f,0.f,0.f}; OaB[i] = (f32x4){0.f,0.f,0.f,0.f}; }
  f32x4 liA = (f32x4){0.f,0.f,0.f,0.f}, liB = (f32x4){0.f,0.f,0.f,0.f};

  unsigned short* pw = &sP[w][0];

  auto stage = [&](int kt, int buf){
    int kbase = kt*64;
    #pragma unroll
    for (int i=0;i<2;i++){
      int cb = (w*2 + i)*64;              // wave-uniform chunk base
      int L = cb + lane;
      int row = L>>3, p = L&7, c = p ^ (row&7);
      GLDS(K  + (size_t)(kbase+row)*Dc + c*8,        &sK[buf][0]  + cb*8);
      GLDS(VT + (size_t)row*Sc + kbase + c*8,        &sVT[buf][0] + cb*8);
    }
  };

  for (int kt=0; kt<=qtB; kt+=2){
    stage(kt, 0);
    bool have2 = (kt+1 <= qtB);
    if (have2) stage(kt+1, 1);
    __syncthreads();                      // drains both stagings; one drain per 2 tiles

    if (kt <= qtA)
      attn_tile(&sK[0][0], &sVT[0][0], pw, qA0, qA1, ones, liA, OaA, kt*64, qwA, quad, m16);
    attn_tile(&sK[0][0], &sVT[0][0], pw, qB0, qB1, ones, liB, OaB, kt*64, qwB, quad, m16);
    if (have2){
      if (kt+1 <= qtA)
        attn_tile(&sK[1][0], &sVT[1][0], pw, qA0, qA1, ones, liA, OaA, (kt+1)*64, qwA, quad, m16);
      attn_tile(&sK[1][0], &sVT[1][0], pw, qB0, qB1, ones, liB, OaB, (kt+1)*64, qwB, quad, m16);
    }
    __syncthreads();                      // protect buffers before next phase overwrite
  }

  // epilogue: O rows s = qw+quad*4+r, cols e = h*64 + tt*16 + m16; li already per-row
  int b = bh >> 4, h = bh & 15;
  float iA[4], iB[4];
  #pragma unroll
  for (int r=0;r<4;r++){ iA[r] = 1.0f/liA[r]; iB[r] = 1.0f/liB[r]; }
  #pragma unroll
  for (int tt=0;tt<4;tt++)
    #pragma unroll
    for (int r=0;r<4;r++){
      int e = h*64 + tt*16 + m16;
      int sA_ = qwA + quad*4 + r;
      int sB_ = qwB + quad*4 + r;
      Ob[((size_t)b*Sc + sA_)*Ec + e] = f2bf(OaA[tt][r]*iA[r]);
      Ob[((size_t)b*Sc + sB_)*Ec + e] = f2bf(OaB[tt][r]*iB[r]);
    }
}

extern "C" void kernel_launch(void* const* d_in, const int* in_sizes, int n_in,
                              void* d_out, int out_size, void* d_ws, size_t ws_size,
                              hipStream_t stream){
  const float* X  = (const float*)d_in[0];
  const float* Wq = (const float*)d_in[1];
  const float* bq = (const float*)d_in[2];
  const float* Wk = (const float*)d_in[3];
  const float* bk = (const float*)d_in[4];
  const float* Wv = (const float*)d_in[5];
  const float* bv = (const float*)d_in[6];
  const float* Wo = (const float*)d_in[7];
  const float* bo = (const float*)d_in[8];

  uint8_t* ws = (uint8_t*)d_ws;
  unsigned short* Xb  = (unsigned short*)(ws);                    // 8 MB
  unsigned short* WT4 = (unsigned short*)(ws + (size_t)(8u<<20)); // 8 MB (WqT,WkT,WvT,WoT)
  unsigned short* QKV = (unsigned short*)(ws + (size_t)(16u<<20));// 24 MB (Q,K,V^T)
  unsigned short* ATT = (unsigned short*)(ws + (size_t)(40u<<20));// 8 MB

  k_prep<<<dim3(5120), 256, 0, stream>>>(X, Xb, Wq, Wk, Wv, Wo, WT4);
  k_qkv<<<dim3(16,32), 256, 0, stream>>>(Xb, WT4, bq, bk, bv, QKV);
  k_attn<<<dim3(16,32), 256, 0, stream>>>(QKV, QKV + (size_t)Mc*Ec, QKV + 2*(size_t)Mc*Ec, ATT);
  k_gemm1<<<dim3(16,32), 256, 0, stream>>>(ATT, WT4 + (size_t)3*Ec*Ec, bo, (float*)d_out);
}